// Round 3
// baseline (150.255 us; speedup 1.0000x reference)
//
#include <hip/hip_runtime.h>

typedef __attribute__((ext_vector_type(8))) short bf16x8;
typedef __attribute__((ext_vector_type(4))) float f32x4;

#define BB 4
#define NN 32
#define CC 32
#define HWD 4096
#define AROW ((size_t)CC * HWD)   // stride between n-rows (floats)

// Instrumentation reps (idempotent bodies; output identical to single-rep)
#define GRAM_REPS 6
#define SM_REPS 40
#define PV_REPS 5

__device__ __forceinline__ unsigned cvt_pk_bf16(float lo, float hi) {
    unsigned r;
    asm("v_cvt_pk_bf16_f32 %0, %1, %2" : "=v"(r) : "v"(lo), "v"(hi));
    return r;
}

__device__ __forceinline__ bf16x8 pack8(float4 a, float4 b) {
    union { unsigned u[4]; bf16x8 v; } u;
    u.u[0] = cvt_pk_bf16(a.x, a.y);
    u.u[1] = cvt_pk_bf16(a.z, a.w);
    u.u[2] = cvt_pk_bf16(b.x, b.y);
    u.u[3] = cvt_pk_bf16(b.z, b.w);
    return u.v;
}

// ---- Kernel 1: Gram partials via MFMA, frags straight from global ----
__global__ __launch_bounds__(256) void k_gram(const float* __restrict__ x,
                                              float* __restrict__ Gp) {
    const int bid = blockIdx.x;
    const int s   = bid & 7;
    const int bc  = bid >> 3;
    const int b   = bc >> 5, c = bc & 31;
    const int tid = threadIdx.x;
    const int w   = tid >> 6, l = tid & 63;
    const int r   = l & 15, g = l >> 4;

    __shared__ float red[4][64][16];

    const float* xb = x + ((size_t)b * NN * CC + c) * HWD;
    const int hwbase = s * 512 + w * 128;
    const float* p0 = xb + (size_t)r        * AROW + hwbase + 8 * g;
    const float* p1 = xb + (size_t)(r + 16) * AROW + hwbase + 8 * g;

#pragma clang loop unroll(disable)
    for (int rep = 0; rep < GRAM_REPS; ++rep) {
        __syncthreads();   // red[] reuse across reps

        f32x4 acc[2][2];
#pragma unroll
        for (int i = 0; i < 2; ++i)
#pragma unroll
            for (int j = 0; j < 2; ++j)
#pragma unroll
                for (int q = 0; q < 4; ++q) acc[i][j][q] = 0.f;

#pragma unroll
        for (int ch = 0; ch < 4; ++ch) {
            const float4 a0 = *(const float4*)(p0 + ch * 32);
            const float4 a1 = *(const float4*)(p0 + ch * 32 + 4);
            const float4 b0 = *(const float4*)(p1 + ch * 32);
            const float4 b1 = *(const float4*)(p1 + ch * 32 + 4);
            const bf16x8 F0 = pack8(a0, a1);
            const bf16x8 F1 = pack8(b0, b1);
            acc[0][0] = __builtin_amdgcn_mfma_f32_16x16x32_bf16(F0, F0, acc[0][0], 0, 0, 0);
            acc[0][1] = __builtin_amdgcn_mfma_f32_16x16x32_bf16(F0, F1, acc[0][1], 0, 0, 0);
            acc[1][0] = __builtin_amdgcn_mfma_f32_16x16x32_bf16(F1, F0, acc[1][0], 0, 0, 0);
            acc[1][1] = __builtin_amdgcn_mfma_f32_16x16x32_bf16(F1, F1, acc[1][1], 0, 0, 0);
        }

#pragma unroll
        for (int ta = 0; ta < 2; ++ta)
#pragma unroll
            for (int tf = 0; tf < 2; ++tf)
#pragma unroll
                for (int q = 0; q < 4; ++q)
                    red[w][l][(ta * 2 + tf) * 4 + q] = acc[ta][tf][q];
        __syncthreads();

        const int a   = tid >> 3;
        const int f0  = 4 * (tid & 7);
        const int lg  = ((a >> 2) & 3) * 16 + (f0 & 15);
        const int reg = ((a >> 4) * 2 + (f0 >> 4)) * 4 + (a & 3);
        float sv[4];
#pragma unroll
        for (int j = 0; j < 4; ++j) {
            float v = 0.f;
#pragma unroll
            for (int ww = 0; ww < 4; ++ww) v += red[ww][lg + j][reg];
            sv[j] = v;
        }
        *(float4*)&Gp[(size_t)bid * 1024 + 4 * tid] = make_float4(sv[0], sv[1], sv[2], sv[3]);

        asm volatile("" ::: "memory");   // block LICM across reps
    }
}

// ---- Kernel 2: reduce 8 splits + scale + softmax + fold wv, emit bf16 Ahat ----
__global__ __launch_bounds__(256) void k_softmax(const float* __restrict__ Gp,
                                                 const float* __restrict__ w,
                                                 unsigned short* __restrict__ Ahat) {
    const int bc = blockIdx.x;
    const int c  = bc & 31;
    const int t  = threadIdx.x;
    const int a  = t >> 3, fo = 4 * (t & 7);

#pragma clang loop unroll(disable)
    for (int rep = 0; rep < SM_REPS; ++rep) {
        float gs[4] = {0.f, 0.f, 0.f, 0.f};
#pragma unroll
        for (int s = 0; s < 8; ++s) {
            const float4 v = *(const float4*)&Gp[(size_t)(bc * 8 + s) * 1024 + a * 32 + fo];
            gs[0] += v.x; gs[1] += v.y; gs[2] += v.z; gs[3] += v.w;
        }
        const float wq = w[(a * CC + c) * 3] * 0.015625f;
        float S[4];
#pragma unroll
        for (int j = 0; j < 4; ++j)
            S[j] = wq * w[((fo + j) * CC + c) * 3 + 1] * gs[j];

        float m = fmaxf(fmaxf(S[0], S[1]), fmaxf(S[2], S[3]));
#pragma unroll
        for (int o = 1; o < 8; o <<= 1) m = fmaxf(m, __shfl_xor(m, o, 64));
        float e[4], sum = 0.f;
#pragma unroll
        for (int j = 0; j < 4; ++j) { e[j] = __expf(S[j] - m); sum += e[j]; }
#pragma unroll
        for (int o = 1; o < 8; o <<= 1) sum += __shfl_xor(sum, o, 64);
        const float inv = 1.f / sum;

        float o0 = e[0] * inv * w[((fo + 0) * CC + c) * 3 + 2];
        float o1 = e[1] * inv * w[((fo + 1) * CC + c) * 3 + 2];
        float o2 = e[2] * inv * w[((fo + 2) * CC + c) * 3 + 2];
        float o3 = e[3] * inv * w[((fo + 3) * CC + c) * 3 + 2];
        uint2 pk = make_uint2(cvt_pk_bf16(o0, o1), cvt_pk_bf16(o2, o3));
        *(uint2*)&Ahat[(size_t)bc * 1024 + a * 32 + fo] = pk;

        asm volatile("" ::: "memory");
    }
}

// ---- Kernel 3: out[a,b,c,hw] = sum_f Ahat[a,f]*x[b,f,c,hw] via MFMA ----
__global__ __launch_bounds__(256) void k_pv(const float* __restrict__ x,
                                            const unsigned short* __restrict__ Ahat,
                                            float* __restrict__ out) {
    const int bid   = blockIdx.x;
    const int chunk = bid & 15;
    const int bc    = bid >> 4;
    const int b     = bc >> 5, c = bc & 31;
    const int tid   = threadIdx.x;
    const int w     = tid >> 6, l = tid & 63;
    const int r     = l & 15, g = l >> 4;

#pragma clang loop unroll(disable)
    for (int rep = 0; rep < PV_REPS; ++rep) {
        const unsigned short* ab = Ahat + (size_t)bc * 1024;
        const bf16x8 A0 = *(const bf16x8*)(ab + r * 32 + 8 * g);
        const bf16x8 A1 = *(const bf16x8*)(ab + (r + 16) * 32 + 8 * g);

        const float* xb = x + ((size_t)b * NN * CC + c) * HWD + chunk * 256 + w * 64;
        const f32x4 zero = {0.f, 0.f, 0.f, 0.f};

#pragma unroll
        for (int ht = 0; ht < 4; ++ht) {
            const int hw = ht * 16 + r;
            const float* bp = xb + (size_t)(8 * g) * AROW + hw;
            float bf[8];
#pragma unroll
            for (int i = 0; i < 8; ++i) bf[i] = bp[(size_t)i * AROW];
            const bf16x8 B = pack8(make_float4(bf[0], bf[1], bf[2], bf[3]),
                                   make_float4(bf[4], bf[5], bf[6], bf[7]));
            f32x4 d0 = __builtin_amdgcn_mfma_f32_16x16x32_bf16(A0, B, zero, 0, 0, 0);
            f32x4 d1 = __builtin_amdgcn_mfma_f32_16x16x32_bf16(A1, B, zero, 0, 0, 0);

            const size_t hwg = (size_t)chunk * 256 + w * 64 + ht * 16 + r;
#pragma unroll
            for (int q = 0; q < 4; ++q) {
                const int arow0 = g * 4 + q;
                out[(((size_t)arow0 * BB + b) * CC + c) * HWD + hwg]        = d0[q];
                out[(((size_t)(arow0 + 16) * BB + b) * CC + c) * HWD + hwg] = d1[q];
            }
        }
        asm volatile("" ::: "memory");
    }
}

extern "C" void kernel_launch(void* const* d_in, const int* in_sizes, int n_in,
                              void* d_out, int out_size, void* d_ws, size_t ws_size,
                              hipStream_t stream) {
    const float* x = (const float*)d_in[0];
    const float* w = (const float*)d_in[1];
    float* outp = (float*)d_out;
    float* Gp = (float*)d_ws;
    unsigned short* Ahat = (unsigned short*)((char*)d_ws + (size_t)4 * 1024 * 1024);

    hipLaunchKernelGGL(k_gram,    dim3(1024), dim3(256), 0, stream, x, Gp);
    hipLaunchKernelGGL(k_softmax, dim3(128),  dim3(256), 0, stream, Gp, w, Ahat);
    hipLaunchKernelGGL(k_pv,      dim3(2048), dim3(256), 0, stream, x, Ahat, outp);
}

// Round 5
// 45.807 us; speedup vs baseline: 3.2802x; 3.2802x over previous
//
#include <hip/hip_runtime.h>

typedef __attribute__((ext_vector_type(8))) short bf16x8;
typedef __attribute__((ext_vector_type(4))) float f32x4;

#define BB 4
#define NN 32
#define CC 32
#define HWD 4096
#define AROW ((size_t)CC * HWD)   // stride between n-rows (floats)

__device__ __forceinline__ unsigned cvt_pk_bf16(float lo, float hi) {
    unsigned r;
    asm("v_cvt_pk_bf16_f32 %0, %1, %2" : "=v"(r) : "v"(lo), "v"(hi));
    return r;
}

__device__ __forceinline__ bf16x8 pack8(float4 a, float4 b) {
    union { unsigned u[4]; bf16x8 v; } u;
    u.u[0] = cvt_pk_bf16(a.x, a.y);
    u.u[1] = cvt_pk_bf16(a.z, a.w);
    u.u[2] = cvt_pk_bf16(b.x, b.y);
    u.u[3] = cvt_pk_bf16(b.z, b.w);
    return u.v;
}

// ---- Kernel 1: Gram partials via MFMA, frags straight from global (R2, proven) ----
// grid 1024 = 128 bc x 8 splits(512 hw); block 256 (4 waves, each 128 hw)
__global__ __launch_bounds__(256) void k_gram(const float* __restrict__ x,
                                              float* __restrict__ Gp) {
    const int bid = blockIdx.x;
    const int s   = bid & 7;
    const int bc  = bid >> 3;
    const int b   = bc >> 5, c = bc & 31;
    const int tid = threadIdx.x;
    const int w   = tid >> 6, l = tid & 63;
    const int r   = l & 15, g = l >> 4;

    const float* xb = x + ((size_t)b * NN * CC + c) * HWD;
    const int hwbase = s * 512 + w * 128;
    const float* p0 = xb + (size_t)r        * AROW + hwbase + 8 * g;
    const float* p1 = xb + (size_t)(r + 16) * AROW + hwbase + 8 * g;

    f32x4 acc[2][2];
#pragma unroll
    for (int i = 0; i < 2; ++i)
#pragma unroll
        for (int j = 0; j < 2; ++j)
#pragma unroll
            for (int q = 0; q < 4; ++q) acc[i][j][q] = 0.f;

#pragma unroll
    for (int ch = 0; ch < 4; ++ch) {
        const float4 a0 = *(const float4*)(p0 + ch * 32);
        const float4 a1 = *(const float4*)(p0 + ch * 32 + 4);
        const float4 b0 = *(const float4*)(p1 + ch * 32);
        const float4 b1 = *(const float4*)(p1 + ch * 32 + 4);
        const bf16x8 F0 = pack8(a0, a1);
        const bf16x8 F1 = pack8(b0, b1);
        acc[0][0] = __builtin_amdgcn_mfma_f32_16x16x32_bf16(F0, F0, acc[0][0], 0, 0, 0);
        acc[0][1] = __builtin_amdgcn_mfma_f32_16x16x32_bf16(F0, F1, acc[0][1], 0, 0, 0);
        acc[1][0] = __builtin_amdgcn_mfma_f32_16x16x32_bf16(F1, F0, acc[1][0], 0, 0, 0);
        acc[1][1] = __builtin_amdgcn_mfma_f32_16x16x32_bf16(F1, F1, acc[1][1], 0, 0, 0);
    }

    __shared__ float red[4][64][16];
#pragma unroll
    for (int ta = 0; ta < 2; ++ta)
#pragma unroll
        for (int tf = 0; tf < 2; ++tf)
#pragma unroll
            for (int q = 0; q < 4; ++q)
                red[w][l][(ta * 2 + tf) * 4 + q] = acc[ta][tf][q];
    __syncthreads();

    const int a   = tid >> 3;
    const int f0  = 4 * (tid & 7);
    const int lg  = ((a >> 2) & 3) * 16 + (f0 & 15);
    const int reg = ((a >> 4) * 2 + (f0 >> 4)) * 4 + (a & 3);
    float sv[4];
#pragma unroll
    for (int j = 0; j < 4; ++j) {
        float v = 0.f;
#pragma unroll
        for (int ww = 0; ww < 4; ++ww) v += red[ww][lg + j][reg];
        sv[j] = v;
    }
    *(float4*)&Gp[(size_t)bid * 1024 + 4 * tid] = make_float4(sv[0], sv[1], sv[2], sv[3]);
}

// ---- Kernel 2: fused softmax + PV ----
// grid 2048 = 128 bc x 16 chunks(256 hw); block 256.
// Per block: (a) redundant softmax for its bc -> Ahat tile in LDS,
// (b) stage x[32f][256hw] as bf16-pairs in swizzled LDS, (c) MFMA, store.
__global__ __launch_bounds__(256) void k_pv(const float* __restrict__ x,
                                            const float* __restrict__ w,
                                            const float* __restrict__ Gp,
                                            float* __restrict__ out) {
    const int bid   = blockIdx.x;
    const int chunk = bid & 15;
    const int bc    = bid >> 4;
    const int b     = bc >> 5, c = bc & 31;
    const int tid   = threadIdx.x;
    const int wv    = tid >> 6, l = tid & 63;
    const int r     = l & 15, g = l >> 4;

    __shared__ unsigned xt[256][16];   // [hw][fpair dword], col = p ^ (hw&12)
    __shared__ unsigned ahat[32][20];  // [a][fpair dword], padded stride

    // ---- (a) softmax for this bc (thread = (a = tid>>3, 4 f at fo)) ----
    {
        const int a = tid >> 3, fo = 4 * (tid & 7);
        float gs[4] = {0.f, 0.f, 0.f, 0.f};
#pragma unroll
        for (int s = 0; s < 8; ++s) {
            const float4 v = *(const float4*)&Gp[(size_t)(bc * 8 + s) * 1024 + a * 32 + fo];
            gs[0] += v.x; gs[1] += v.y; gs[2] += v.z; gs[3] += v.w;
        }
        const float wq = w[(a * CC + c) * 3] * 0.015625f;   // 1/sqrt(4096)
        float S[4];
#pragma unroll
        for (int j = 0; j < 4; ++j)
            S[j] = wq * w[((fo + j) * CC + c) * 3 + 1] * gs[j];

        float m = fmaxf(fmaxf(S[0], S[1]), fmaxf(S[2], S[3]));
#pragma unroll
        for (int o = 1; o < 8; o <<= 1) m = fmaxf(m, __shfl_xor(m, o, 64));
        float e[4], sum = 0.f;
#pragma unroll
        for (int j = 0; j < 4; ++j) { e[j] = __expf(S[j] - m); sum += e[j]; }
#pragma unroll
        for (int o = 1; o < 8; o <<= 1) sum += __shfl_xor(sum, o, 64);
        const float inv = 1.f / sum;

        const float o0 = e[0] * inv * w[((fo + 0) * CC + c) * 3 + 2];
        const float o1 = e[1] * inv * w[((fo + 1) * CC + c) * 3 + 2];
        const float o2 = e[2] * inv * w[((fo + 2) * CC + c) * 3 + 2];
        const float o3 = e[3] * inv * w[((fo + 3) * CC + c) * 3 + 2];
        ahat[a][2 * (tid & 7) + 0] = cvt_pk_bf16(o0, o1);
        ahat[a][2 * (tid & 7) + 1] = cvt_pk_bf16(o2, o3);
    }

    // ---- (b) stage x[f][hw] tile: coalesced float4 loads, swizzled LDS ----
    {
        const int p = tid >> 4;          // f-pair index 0..15 (f = 2p, 2p+1)
        const int q = tid & 15;
        const float* xr0 = x + ((size_t)(b * NN + 2 * p) * CC + c) * HWD + chunk * 256;
        const float* xr1 = xr0 + AROW;
#pragma unroll
        for (int k = 0; k < 4; ++k) {
            const int hwc = 4 * (q + 16 * k);
            const float4 fa = *(const float4*)(xr0 + hwc);
            const float4 fb = *(const float4*)(xr1 + hwc);
            const float av[4] = {fa.x, fa.y, fa.z, fa.w};
            const float bv[4] = {fb.x, fb.y, fb.z, fb.w};
#pragma unroll
            for (int i = 0; i < 4; ++i) {
                const int hw = hwc + i;
                xt[hw][p ^ (hw & 12)] = cvt_pk_bf16(av[i], bv[i]);
            }
        }
    }
    __syncthreads();

    // ---- (c) MFMA + store ----
    const bf16x8 A0 = *(const bf16x8*)&ahat[r][4 * g];        // rows 0-15, f 8g..8g+7
    const bf16x8 A1 = *(const bf16x8*)&ahat[r + 16][4 * g];   // rows 16-31
    const f32x4 zero = {0.f, 0.f, 0.f, 0.f};

#pragma unroll
    for (int ht = 0; ht < 4; ++ht) {
        const int hw = wv * 64 + ht * 16 + r;                 // local hw (col of B)
        const bf16x8 B = *(const bf16x8*)&xt[hw][4 * (g ^ ((hw >> 2) & 3))];
        f32x4 d0 = __builtin_amdgcn_mfma_f32_16x16x32_bf16(A0, B, zero, 0, 0, 0);
        f32x4 d1 = __builtin_amdgcn_mfma_f32_16x16x32_bf16(A1, B, zero, 0, 0, 0);

        const size_t hwg = (size_t)chunk * 256 + hw;
#pragma unroll
        for (int q2 = 0; q2 < 4; ++q2) {
            const int a0r = g * 4 + q2;
            out[(((size_t)a0r * BB + b) * CC + c) * HWD + hwg]        = d0[q2];
            out[(((size_t)(a0r + 16) * BB + b) * CC + c) * HWD + hwg] = d1[q2];
        }
    }
}

extern "C" void kernel_launch(void* const* d_in, const int* in_sizes, int n_in,
                              void* d_out, int out_size, void* d_ws, size_t ws_size,
                              hipStream_t stream) {
    const float* x = (const float*)d_in[0];
    const float* w = (const float*)d_in[1];
    float* outp = (float*)d_out;
    float* Gp = (float*)d_ws;   // 1024 blocks * 1024 f32 = 4 MB

    hipLaunchKernelGGL(k_gram, dim3(1024), dim3(256), 0, stream, x, Gp);
    hipLaunchKernelGGL(k_pv,   dim3(2048), dim3(256), 0, stream, x, w, Gp, outp);
}